// Round 2
// baseline (621.998 us; speedup 1.0000x reference)
//
#include <hip/hip_runtime.h>

#define TMASK 32767u
#define P2 2654435761u
#define P3 805459861u

typedef float f32x4 __attribute__((ext_vector_type(4)));

// Resolutions: floor(16 * 2^(l/3)) for l=0..15 (b = exp(ln(32)/15) = 2^(1/3))
__global__ __launch_bounds__(256) void hashgrid_kernel(
    const float* __restrict__ x, const float* __restrict__ tables,
    float* __restrict__ out, int n)
{
    const int i = blockIdx.x * blockDim.x + threadIdx.x;
    if (i >= n) return;

    const size_t xb = 3ull * (size_t)i;
    const float px = __builtin_nontemporal_load(x + xb + 0);
    const float py = __builtin_nontemporal_load(x + xb + 1);
    const float pz = __builtin_nontemporal_load(x + xb + 2);

    // normalize to [0,1]:  (x + RANGE) / (2*RANGE), RANGE = 1
    const float x01 = (px + 1.0f) * 0.5f;
    const float y01 = (py + 1.0f) * 0.5f;
    const float z01 = (pz + 1.0f) * 0.5f;

    constexpr int RES[16] = {16, 20, 25, 32, 40, 50, 64, 80,
                             101, 128, 161, 203, 256, 322, 406, 512};

    float o[32];

    #pragma unroll
    for (int l = 0; l < 16; ++l) {
        const float rf = (float)RES[l];
        const float xs = x01 * rf;
        const float ys = y01 * rf;
        const float zs = z01 * rf;
        const float fxs = floorf(xs), fys = floorf(ys), fzs = floorf(zs);
        const float tx = xs - fxs, ty = ys - fys, tz = zs - fzs;
        const unsigned xi = (unsigned)fxs;
        const unsigned yi = (unsigned)fys;
        const unsigned zi = (unsigned)fzs;

        // hash parts per axis; (a^b)&m == (a&m)^(b&m), and (v+1)*P == v*P + P (mod 2^32)
        const unsigned hx0 = xi & TMASK;
        const unsigned hx1 = (xi + 1u) & TMASK;
        const unsigned hym = yi * P2;
        const unsigned hy0 = hym & TMASK;
        const unsigned hy1 = (hym + P2) & TMASK;
        const unsigned hzm = zi * P3;
        const unsigned hz0 = hzm & TMASK;
        const unsigned hz1 = (hzm + P3) & TMASK;

        const float wx0 = 1.0f - tx;
        const float wy0 = 1.0f - ty;
        const float wz0 = 1.0f - tz;

        const float* tbl = tables + (size_t)l * (32768ull * 2ull);

        float a0 = 0.0f, a1 = 0.0f;
        #pragma unroll
        for (int c = 0; c < 8; ++c) {
            const unsigned hx = (c & 1) ? hx1 : hx0;
            const unsigned hy = (c & 2) ? hy1 : hy0;
            const unsigned hz = (c & 4) ? hz1 : hz0;
            const float    w = ((c & 1) ? tx : wx0) *
                               ((c & 2) ? ty : wy0) *
                               ((c & 4) ? tz : wz0);
            const unsigned idx = hx ^ hy ^ hz;
            const float2 f = *(const float2*)(tbl + 2u * idx);
            a0 = fmaf(w, f.x, a0);
            a1 = fmaf(w, f.y, a1);
        }
        o[2 * l]     = a0;
        o[2 * l + 1] = a1;
    }

    // 32 contiguous floats per point -> 8x 16B nontemporal stores
    // (streaming 128 MB output must not evict the 4 MB tables from L2)
    f32x4* dst = (f32x4*)(out + (size_t)i * 32ull);
    #pragma unroll
    for (int j = 0; j < 8; ++j) {
        f32x4 v = { o[4 * j + 0], o[4 * j + 1], o[4 * j + 2], o[4 * j + 3] };
        __builtin_nontemporal_store(v, dst + j);
    }
}

extern "C" void kernel_launch(void* const* d_in, const int* in_sizes, int n_in,
                              void* d_out, int out_size, void* d_ws, size_t ws_size,
                              hipStream_t stream) {
    const float* x      = (const float*)d_in[0];
    const float* tables = (const float*)d_in[1];
    float* out          = (float*)d_out;

    const int n = in_sizes[0] / 3;          // 1048576 points
    const int block = 256;
    const int grid = (n + block - 1) / block;

    hipLaunchKernelGGL(hashgrid_kernel, dim3(grid), dim3(block), 0, stream,
                       x, tables, out, n);
}

// Round 3
// 435.104 us; speedup vs baseline: 1.4295x; 1.4295x over previous
//
#include <hip/hip_runtime.h>

#define TMASK 32767u
#define P2 2654435761u
#define P3 805459861u

typedef float f32x4 __attribute__((ext_vector_type(4)));

constexpr int BLOCK = 128;
constexpr int PITCH = 33;   // 32 feats + 1 pad float -> write banks (t + 2l) % 32, conflict-free

// Resolutions: floor(16 * 2^(l/3)) for l=0..15
__global__ __launch_bounds__(BLOCK) void hashgrid_kernel(
    const float* __restrict__ xin, const float* __restrict__ tables,
    float* __restrict__ out, int n)
{
    __shared__ float lds[BLOCK * PITCH];
    const int t = threadIdx.x;
    const int base = blockIdx.x * BLOCK;
    const int i = base + t;
    const bool valid = (i < n);

    float px = 0.f, py = 0.f, pz = 0.f;
    if (valid) {
        const size_t xb = 3ull * (size_t)i;
        px = __builtin_nontemporal_load(xin + xb + 0);
        py = __builtin_nontemporal_load(xin + xb + 1);
        pz = __builtin_nontemporal_load(xin + xb + 2);
    }
    // normalize to [0,1]: (x + 1) / 2
    const float x01 = (px + 1.0f) * 0.5f;
    const float y01 = (py + 1.0f) * 0.5f;
    const float z01 = (pz + 1.0f) * 0.5f;

    constexpr int RES[16] = {16, 20, 25, 32, 40, 50, 64, 80,
                             101, 128, 161, 203, 256, 322, 406, 512};

    #pragma unroll
    for (int l = 0; l < 16; ++l) {
        const float rf = (float)RES[l];
        const float xs = x01 * rf, ys = y01 * rf, zs = z01 * rf;
        const float fxs = floorf(xs), fys = floorf(ys), fzs = floorf(zs);
        const float tx = xs - fxs, ty = ys - fys, tz = zs - fzs;
        const unsigned xi = (unsigned)fxs;
        const unsigned yi = (unsigned)fys;
        const unsigned zi = (unsigned)fzs;

        // per-axis hash parts; (a^b)&m == (a&m)^(b&m); (v+1)*P == v*P + P (mod 2^32)
        const unsigned hx0 = xi & TMASK;          // xi <= 512, so hx1 = hx0 + 1
        const unsigned hym = yi * P2;
        const unsigned hy0 = hym & TMASK;
        const unsigned hy1 = (hym + P2) & TMASK;
        const unsigned hzm = zi * P3;
        const unsigned hz0 = hzm & TMASK;
        const unsigned hz1 = (hzm + P3) & TMASK;

        const float wx0 = 1.f - tx, wy0 = 1.f - ty, wz0 = 1.f - tz;
        const bool xeven = (xi & 1u) == 0u;       // even -> x-pair is adjacent entries
        const float* tbl = tables + (size_t)l * 65536ull;

        float a0 = 0.f, a1 = 0.f;
        #pragma unroll
        for (int p = 0; p < 4; ++p) {
            const unsigned m  = ((p & 1) ? hy1 : hy0) ^ ((p & 2) ? hz1 : hz0);
            const float  wyz  = ((p & 1) ? ty : wy0) * ((p & 2) ? tz : wz0);
            const unsigned idx0 = hx0 ^ m;
            const unsigned e    = idx0 & ~1u;
            // 16B load at even entry never crosses a 64B sector; covers entries e, e+1
            const f32x4 q = *(const f32x4*)(tbl + 2u * e);
            const bool lo = (idx0 & 1u) == 0u;
            const float c0x = lo ? q[0] : q[2];
            const float c0y = lo ? q[1] : q[3];
            float c1x, c1y;
            if (xeven) {
                // idx1 = idx0 ^ 1 -> the other half of q, no extra load
                c1x = lo ? q[2] : q[0];
                c1y = lo ? q[3] : q[1];
            } else {
                const unsigned idx1 = (hx0 + 1u) ^ m;
                const float2 f = *(const float2*)(tbl + 2u * idx1);
                c1x = f.x; c1y = f.y;
            }
            const float w0 = wyz * wx0;   // lower x corner: weight (1 - tx)
            const float w1 = wyz * tx;    // upper x corner: weight tx
            a0 = fmaf(w0, c0x, fmaf(w1, c1x, a0));
            a1 = fmaf(w0, c0y, fmaf(w1, c1y, a1));
        }
        lds[t * PITCH + 2 * l]     = a0;
        lds[t * PITCH + 2 * l + 1] = a1;
    }

    __syncthreads();

    // coalesced nontemporal output: BLOCK points x 32 floats, 1KB contiguous per wave-store
    f32x4* ob4 = (f32x4*)(out + (size_t)base * 32ull);
    const int nf4 = (min(n - base, BLOCK)) * 8;   // valid float4s in this block
    #pragma unroll
    for (int j = 0; j < 8; ++j) {
        const int g = j * BLOCK + t;
        if (g < nf4) {
            const int p = g >> 3;
            const int e = (g & 7) * 4;
            const float* s = &lds[p * PITCH + e];
            f32x4 v = { s[0], s[1], s[2], s[3] };
            __builtin_nontemporal_store(v, ob4 + g);
        }
    }
}

extern "C" void kernel_launch(void* const* d_in, const int* in_sizes, int n_in,
                              void* d_out, int out_size, void* d_ws, size_t ws_size,
                              hipStream_t stream) {
    const float* x      = (const float*)d_in[0];
    const float* tables = (const float*)d_in[1];
    float* out          = (float*)d_out;

    const int n = in_sizes[0] / 3;          // 1048576 points
    const int grid = (n + BLOCK - 1) / BLOCK;

    hipLaunchKernelGGL(hashgrid_kernel, dim3(grid), dim3(BLOCK), 0, stream,
                       x, tables, out, n);
}

// Round 4
// 432.371 us; speedup vs baseline: 1.4386x; 1.0063x over previous
//
#include <hip/hip_runtime.h>

#define TMASK 32767u
#define P2 2654435761u
#define P3 805459861u

typedef float f32x4 __attribute__((ext_vector_type(4)));

constexpr int BLOCK = 128;
constexpr int HP = 17;   // half-pitch: 16 feats + 1 pad (odd stride -> conflict-light)

// Resolutions: floor(16 * 2^(l/3)) for l=0..15
__global__ __launch_bounds__(BLOCK, 8) void hashgrid_kernel(
    const float* __restrict__ xin, const float* __restrict__ tables,
    float* __restrict__ out, int n)
{
    __shared__ float lds[BLOCK * HP];    // 8.7 KB -> wave-slot-capped occupancy (~32 waves/CU)
    const int t = threadIdx.x;
    const int base = blockIdx.x * BLOCK;
    const int i = base + t;

    float px = 0.f, py = 0.f, pz = 0.f;
    if (i < n) {
        const size_t xb = 3ull * (size_t)i;
        px = __builtin_nontemporal_load(xin + xb + 0);
        py = __builtin_nontemporal_load(xin + xb + 1);
        pz = __builtin_nontemporal_load(xin + xb + 2);
    }
    // normalize to [0,1]: (x + 1) / 2
    const float x01 = (px + 1.0f) * 0.5f;
    const float y01 = (py + 1.0f) * 0.5f;
    const float z01 = (pz + 1.0f) * 0.5f;

    constexpr int RES[16] = {16, 20, 25, 32, 40, 50, 64, 80,
                             101, 128, 161, 203, 256, 322, 406, 512};

    const int nf4 = min(n - base, BLOCK) * 4;   // valid float4s per half-store

    #pragma unroll
    for (int h = 0; h < 2; ++h) {
        // ---- compute 8 levels into LDS ----
        #pragma unroll
        for (int lo = 0; lo < 8; ++lo) {
            const int l = h * 8 + lo;
            const float rf = (float)RES[l];
            const float xs = x01 * rf, ys = y01 * rf, zs = z01 * rf;
            const float fxs = floorf(xs), fys = floorf(ys), fzs = floorf(zs);
            const float tx = xs - fxs, ty = ys - fys, tz = zs - fzs;
            const unsigned xi = (unsigned)fxs;
            const unsigned yi = (unsigned)fys;
            const unsigned zi = (unsigned)fzs;

            // per-axis hash parts; (a^b)&m == (a&m)^(b&m); (v+1)*P == v*P + P (mod 2^32)
            const unsigned hx0 = xi & TMASK;          // PRIME[0]=1; hx1 = hx0 + 1
            const unsigned hym = yi * P2;
            const unsigned hy0 = hym & TMASK;
            const unsigned hy1 = (hym + P2) & TMASK;
            const unsigned hzm = zi * P3;
            const unsigned hz0 = hzm & TMASK;
            const unsigned hz1 = (hzm + P3) & TMASK;

            const float wx0 = 1.f - tx, wy0 = 1.f - ty, wz0 = 1.f - tz;
            const bool xeven = (xi & 1u) == 0u;       // even -> x-pair is adjacent entries
            const float* tbl = tables + (size_t)l * 65536ull;

            float a0 = 0.f, a1 = 0.f;
            #pragma unroll
            for (int p = 0; p < 4; ++p) {
                const unsigned m  = ((p & 1) ? hy1 : hy0) ^ ((p & 2) ? hz1 : hz0);
                const float  wyz  = ((p & 1) ? ty : wy0) * ((p & 2) ? tz : wz0);
                const unsigned idx0 = hx0 ^ m;
                const unsigned e    = idx0 & ~1u;
                // 16B aligned load covers entries {e, e+1}, never splits a 64B sector
                const f32x4 q = *(const f32x4*)(tbl + 2u * e);
                const bool lo2 = (idx0 & 1u) == 0u;
                const float c0x = lo2 ? q[0] : q[2];
                const float c0y = lo2 ? q[1] : q[3];
                float c1x, c1y;
                if (xeven) {
                    // idx1 = idx0 ^ 1 -> other half of q, no extra load
                    c1x = lo2 ? q[2] : q[0];
                    c1y = lo2 ? q[3] : q[1];
                } else {
                    const unsigned idx1 = (hx0 + 1u) ^ m;
                    const float2 f = *(const float2*)(tbl + 2u * idx1);
                    c1x = f.x; c1y = f.y;
                }
                const float w0 = wyz * wx0;   // lower x corner
                const float w1 = wyz * tx;    // upper x corner
                a0 = fmaf(w0, c0x, fmaf(w1, c1x, a0));
                a1 = fmaf(w0, c0y, fmaf(w1, c1y, a1));
            }
            lds[t * HP + 2 * lo]     = a0;
            lds[t * HP + 2 * lo + 1] = a1;
        }

        __syncthreads();

        // ---- store this half: each point's 64B half-row, via contiguous 16B nt stores ----
        #pragma unroll
        for (int j = 0; j < 4; ++j) {
            const int g = j * BLOCK + t;      // float4 index within this half
            if (g < nf4) {
                const int p = g >> 2;          // point within block
                const int e = (g & 3) * 4;     // feat offset within half (0,4,8,12)
                const float* s = &lds[p * HP + e];
                f32x4 v = { s[0], s[1], s[2], s[3] };
                __builtin_nontemporal_store(
                    v, (f32x4*)(out + (size_t)(base + p) * 32ull + (size_t)(h * 16 + e)));
            }
        }
        __syncthreads();   // protect LDS before next half rewrites it
    }
}

extern "C" void kernel_launch(void* const* d_in, const int* in_sizes, int n_in,
                              void* d_out, int out_size, void* d_ws, size_t ws_size,
                              hipStream_t stream) {
    const float* x      = (const float*)d_in[0];
    const float* tables = (const float*)d_in[1];
    float* out          = (float*)d_out;

    const int n = in_sizes[0] / 3;          // 1048576 points
    const int grid = (n + BLOCK - 1) / BLOCK;

    hipLaunchKernelGGL(hashgrid_kernel, dim3(grid), dim3(BLOCK), 0, stream,
                       x, tables, out, n);
}

// Round 5
// 395.235 us; speedup vs baseline: 1.5737x; 1.0940x over previous
//
#include <hip/hip_runtime.h>

#define TMASK 32767u
#define P2 2654435761u
#define P3 805459861u

typedef float f32x4 __attribute__((ext_vector_type(4)));

constexpr int NBINS = 32768;     // 32^3 Morton bins (~32 pts/bin at 1M points)
constexpr int BLOCK = 128;
constexpr int HP = 17;           // half-row pitch: 16 feats + 1 pad

// ---------- ws layout ----------
// [0, 128KB)        : hist   (32768 u32)
// [128KB, 256KB)    : cursor (32768 u32)  -- exclusive offsets, consumed by scatter
// [256KB, 256KB+16MB): sortedx (n * float4 {x,y,z,bitcast(orig)})
constexpr size_t WS_HIST   = 0;
constexpr size_t WS_CURSOR = 128 * 1024;
constexpr size_t WS_SORTED = 256 * 1024;
constexpr size_t WS_NEEDED = WS_SORTED + (size_t)1048576 * 16;

__device__ __forceinline__ unsigned part1by2(unsigned v) {
    v &= 0x3FFu;
    v = (v | (v << 16)) & 0x030000FFu;
    v = (v | (v << 8))  & 0x0300F00Fu;
    v = (v | (v << 4))  & 0x030C30C3u;
    v = (v | (v << 2))  & 0x09249249u;
    return v;
}

__device__ __forceinline__ unsigned morton_key(float x01, float y01, float z01) {
    const unsigned cx = min(31u, (unsigned)(x01 * 32.0f));
    const unsigned cy = min(31u, (unsigned)(y01 * 32.0f));
    const unsigned cz = min(31u, (unsigned)(z01 * 32.0f));
    return part1by2(cx) | (part1by2(cy) << 1) | (part1by2(cz) << 2);
}

__global__ void zero_hist_kernel(unsigned* __restrict__ hist) {
    const int i = blockIdx.x * blockDim.x + threadIdx.x;
    if (i < NBINS) hist[i] = 0u;
}

__global__ void hist_kernel(const float* __restrict__ xin, unsigned* __restrict__ hist, int n) {
    const int i = blockIdx.x * blockDim.x + threadIdx.x;
    if (i >= n) return;
    const size_t b = 3ull * (size_t)i;
    const float x01 = (xin[b + 0] + 1.0f) * 0.5f;
    const float y01 = (xin[b + 1] + 1.0f) * 0.5f;
    const float z01 = (xin[b + 2] + 1.0f) * 0.5f;
    atomicAdd(&hist[morton_key(x01, y01, z01)], 1u);
}

// exclusive scan of 32768 bins; one block of 1024 threads, 32 bins each
__global__ __launch_bounds__(1024) void scan_kernel(const unsigned* __restrict__ hist,
                                                    unsigned* __restrict__ cursor) {
    __shared__ unsigned sums[1024];
    const int t = threadIdx.x;
    const int base = t * 32;
    unsigned loc[32];
    unsigned s = 0;
    #pragma unroll
    for (int k = 0; k < 32; ++k) { loc[k] = s; s += hist[base + k]; }
    sums[t] = s;
    __syncthreads();
    for (int off = 1; off < 1024; off <<= 1) {
        const unsigned v = (t >= off) ? sums[t - off] : 0u;
        __syncthreads();
        sums[t] += v;
        __syncthreads();
    }
    const unsigned excl = sums[t] - s;   // exclusive prefix for this thread's chunk
    #pragma unroll
    for (int k = 0; k < 32; ++k) cursor[base + k] = excl + loc[k];
}

__global__ void scatter_kernel(const float* __restrict__ xin, unsigned* __restrict__ cursor,
                               f32x4* __restrict__ sortedx, int n) {
    const int i = blockIdx.x * blockDim.x + threadIdx.x;
    if (i >= n) return;
    const size_t b = 3ull * (size_t)i;
    const float px = xin[b + 0], py = xin[b + 1], pz = xin[b + 2];
    const float x01 = (px + 1.0f) * 0.5f;
    const float y01 = (py + 1.0f) * 0.5f;
    const float z01 = (pz + 1.0f) * 0.5f;
    const unsigned k = morton_key(x01, y01, z01);
    const unsigned slot = atomicAdd(&cursor[k], 1u);
    f32x4 v = { px, py, pz, __uint_as_float((unsigned)i) };
    sortedx[slot] = v;
}

// Resolutions: floor(16 * 2^(l/3)) for l=0..15
__global__ __launch_bounds__(BLOCK, 8) void hashgrid_kernel(
    const float* __restrict__ xin, const f32x4* __restrict__ sortedx,
    const float* __restrict__ tables, float* __restrict__ out, int n, int sorted)
{
    __shared__ float lds[BLOCK * HP];
    __shared__ unsigned sorig[BLOCK];
    const int t = threadIdx.x;
    const int base = blockIdx.x * BLOCK;
    const int i = base + t;

    float px = 0.f, py = 0.f, pz = 0.f;
    unsigned orig = (unsigned)i;
    if (i < n) {
        if (sorted) {
            const f32x4 v = sortedx[i];
            px = v[0]; py = v[1]; pz = v[2];
            orig = __float_as_uint(v[3]);
        } else {
            const size_t xb = 3ull * (size_t)i;
            px = xin[xb + 0]; py = xin[xb + 1]; pz = xin[xb + 2];
        }
    }
    sorig[t] = orig;

    const float x01 = (px + 1.0f) * 0.5f;
    const float y01 = (py + 1.0f) * 0.5f;
    const float z01 = (pz + 1.0f) * 0.5f;

    constexpr int RES[16] = {16, 20, 25, 32, 40, 50, 64, 80,
                             101, 128, 161, 203, 256, 322, 406, 512};

    const int nf4 = min(n - base, BLOCK) * 4;   // valid float4s per half-store

    #pragma unroll
    for (int h = 0; h < 2; ++h) {
        #pragma unroll
        for (int lo = 0; lo < 8; ++lo) {
            const int l = h * 8 + lo;
            const float rf = (float)RES[l];
            const float xs = x01 * rf, ys = y01 * rf, zs = z01 * rf;
            const float fxs = floorf(xs), fys = floorf(ys), fzs = floorf(zs);
            const float tx = xs - fxs, ty = ys - fys, tz = zs - fzs;
            const unsigned xi = (unsigned)fxs;
            const unsigned yi = (unsigned)fys;
            const unsigned zi = (unsigned)fzs;

            // per-axis hash parts; (a^b)&m == (a&m)^(b&m); (v+1)*P == v*P + P (mod 2^32)
            const unsigned hx0 = xi & TMASK;      // PRIME[0]=1; upper-x hash = hx0 + 1
            const unsigned hym = yi * P2;
            const unsigned hy0 = hym & TMASK;
            const unsigned hy1 = (hym + P2) & TMASK;
            const unsigned hzm = zi * P3;
            const unsigned hz0 = hzm & TMASK;
            const unsigned hz1 = (hzm + P3) & TMASK;

            const float wx0 = 1.f - tx, wy0 = 1.f - ty, wz0 = 1.f - tz;
            const bool xeven = (xi & 1u) == 0u;
            const float* tbl = tables + (size_t)l * 65536ull;

            float a0 = 0.f, a1 = 0.f;
            #pragma unroll
            for (int p = 0; p < 4; ++p) {
                const unsigned m  = ((p & 1) ? hy1 : hy0) ^ ((p & 2) ? hz1 : hz0);
                const float  wyz  = ((p & 1) ? ty : wy0) * ((p & 2) ? tz : wz0);
                const unsigned idx0 = hx0 ^ m;
                const unsigned e    = idx0 & ~1u;
                // aligned 16B load covers entries {e, e+1}; if xi even, both x-corners
                const f32x4 q = *(const f32x4*)(tbl + 2u * e);
                const bool lo2 = (idx0 & 1u) == 0u;
                const float c0x = lo2 ? q[0] : q[2];
                const float c0y = lo2 ? q[1] : q[3];
                float c1x, c1y;
                if (xeven) {
                    c1x = lo2 ? q[2] : q[0];
                    c1y = lo2 ? q[3] : q[1];
                } else {
                    const unsigned idx1 = (hx0 + 1u) ^ m;
                    const float2 f = *(const float2*)(tbl + 2u * idx1);
                    c1x = f.x; c1y = f.y;
                }
                const float w0 = wyz * wx0;
                const float w1 = wyz * tx;
                a0 = fmaf(w0, c0x, fmaf(w1, c1x, a0));
                a1 = fmaf(w0, c0y, fmaf(w1, c1y, a1));
            }
            lds[t * HP + 2 * lo]     = a0;
            lds[t * HP + 2 * lo + 1] = a1;
        }

        __syncthreads();

        // store this half: 4 consecutive lanes emit one point's 64B half-row (full line)
        #pragma unroll
        for (int j = 0; j < 4; ++j) {
            const int g = j * BLOCK + t;
            if (g < nf4) {
                const int p = g >> 2;
                const int e = (g & 3) * 4;
                const float* s = &lds[p * HP + e];
                f32x4 v = { s[0], s[1], s[2], s[3] };
                __builtin_nontemporal_store(
                    v, (f32x4*)(out + (size_t)sorig[p] * 32ull + (size_t)(h * 16 + e)));
            }
        }
        __syncthreads();
    }
}

extern "C" void kernel_launch(void* const* d_in, const int* in_sizes, int n_in,
                              void* d_out, int out_size, void* d_ws, size_t ws_size,
                              hipStream_t stream) {
    const float* x      = (const float*)d_in[0];
    const float* tables = (const float*)d_in[1];
    float* out          = (float*)d_out;

    const int n = in_sizes[0] / 3;          // 1048576 points
    const int sorted = (ws_size >= WS_NEEDED) ? 1 : 0;

    f32x4* sortedx = (f32x4*)((char*)d_ws + WS_SORTED);

    if (sorted) {
        unsigned* hist   = (unsigned*)((char*)d_ws + WS_HIST);
        unsigned* cursor = (unsigned*)((char*)d_ws + WS_CURSOR);
        hipLaunchKernelGGL(zero_hist_kernel, dim3(NBINS / 256), dim3(256), 0, stream, hist);
        hipLaunchKernelGGL(hist_kernel, dim3((n + 255) / 256), dim3(256), 0, stream,
                           x, hist, n);
        hipLaunchKernelGGL(scan_kernel, dim3(1), dim3(1024), 0, stream, hist, cursor);
        hipLaunchKernelGGL(scatter_kernel, dim3((n + 255) / 256), dim3(256), 0, stream,
                           x, cursor, sortedx, n);
    }

    hipLaunchKernelGGL(hashgrid_kernel, dim3((n + BLOCK - 1) / BLOCK), dim3(BLOCK), 0, stream,
                       x, sortedx, tables, out, n, sorted);
}

// Round 6
// 392.885 us; speedup vs baseline: 1.5832x; 1.0060x over previous
//
#include <hip/hip_runtime.h>

#define TMASK 32767u
#define P2 2654435761u
#define P3 805459861u

typedef float f32x4 __attribute__((ext_vector_type(4)));
typedef unsigned u32x4 __attribute__((ext_vector_type(4)));

constexpr int NBINS = 32768;     // 32^3 Morton bins (~32 pts/bin at 1M points)
constexpr int BLOCK = 128;
constexpr int HP = 17;           // half-row pitch: 16 feats + 1 pad

// ---------- ws layout ----------
constexpr size_t WS_HIST   = 0;
constexpr size_t WS_CURSOR = 128 * 1024;
constexpr size_t WS_SORTED = 256 * 1024;
constexpr size_t WS_NEEDED = WS_SORTED + (size_t)1048576 * 16;

__device__ __forceinline__ unsigned part1by2(unsigned v) {
    v &= 0x3FFu;
    v = (v | (v << 16)) & 0x030000FFu;
    v = (v | (v << 8))  & 0x0300F00Fu;
    v = (v | (v << 4))  & 0x030C30C3u;
    v = (v | (v << 2))  & 0x09249249u;
    return v;
}

__device__ __forceinline__ unsigned morton_key(float px, float py, float pz) {
    const float x01 = (px + 1.0f) * 0.5f;
    const float y01 = (py + 1.0f) * 0.5f;
    const float z01 = (pz + 1.0f) * 0.5f;
    const unsigned cx = min(31u, (unsigned)(x01 * 32.0f));
    const unsigned cy = min(31u, (unsigned)(y01 * 32.0f));
    const unsigned cz = min(31u, (unsigned)(z01 * 32.0f));
    return part1by2(cx) | (part1by2(cy) << 1) | (part1by2(cz) << 2);
}

__global__ void zero_hist_kernel(unsigned* __restrict__ hist) {
    const int i = blockIdx.x * blockDim.x + threadIdx.x;
    if (i < NBINS) hist[i] = 0u;
}

// 4 points per thread, 3x aligned 16B loads
__global__ __launch_bounds__(256) void hist_kernel(const float* __restrict__ xin,
                                                   unsigned* __restrict__ hist, int n) {
    const int j = blockIdx.x * blockDim.x + threadIdx.x;
    const int p0 = j * 4;
    if (p0 + 3 < n) {
        const f32x4* xb = (const f32x4*)(xin + (size_t)p0 * 3);
        const f32x4 a = __builtin_nontemporal_load(xb + 0);   // x0 y0 z0 x1
        const f32x4 b = __builtin_nontemporal_load(xb + 1);   // y1 z1 x2 y2
        const f32x4 c = __builtin_nontemporal_load(xb + 2);   // z2 x3 y3 z3
        atomicAdd(&hist[morton_key(a[0], a[1], a[2])], 1u);
        atomicAdd(&hist[morton_key(a[3], b[0], b[1])], 1u);
        atomicAdd(&hist[morton_key(b[2], b[3], c[0])], 1u);
        atomicAdd(&hist[morton_key(c[1], c[2], c[3])], 1u);
    } else {
        for (int p = p0; p < n; ++p) {
            const size_t bb = 3ull * (size_t)p;
            atomicAdd(&hist[morton_key(xin[bb], xin[bb + 1], xin[bb + 2])], 1u);
        }
    }
}

// exclusive scan of 32768 bins; 1024 threads, 32 bins each, shfl-based (2 barriers)
__global__ __launch_bounds__(1024) void scan_kernel(const unsigned* __restrict__ hist,
                                                    unsigned* __restrict__ cursor) {
    const int t = threadIdx.x;
    const u32x4* h4 = (const u32x4*)hist;
    u32x4 v[8];
    #pragma unroll
    for (int k = 0; k < 8; ++k) v[k] = h4[t * 8 + k];

    unsigned loc[32];
    unsigned s = 0;
    #pragma unroll
    for (int k = 0; k < 8; ++k) {
        loc[4 * k + 0] = s; s += v[k][0];
        loc[4 * k + 1] = s; s += v[k][1];
        loc[4 * k + 2] = s; s += v[k][2];
        loc[4 * k + 3] = s; s += v[k][3];
    }

    const int lane = t & 63;
    unsigned inc = s;                       // inclusive-scan of thread totals within wave
    #pragma unroll
    for (int off = 1; off < 64; off <<= 1) {
        const unsigned u = __shfl_up(inc, off, 64);
        if (lane >= off) inc += u;
    }

    __shared__ unsigned wtot[16];
    if (lane == 63) wtot[t >> 6] = inc;     // wave total
    __syncthreads();
    if (t < 16) {                           // exclusive scan of 16 wave totals
        unsigned w = wtot[t];
        const unsigned orig = w;
        #pragma unroll
        for (int off = 1; off < 16; off <<= 1) {
            const unsigned u = __shfl_up(w, off, 16);
            if (t >= off) w += u;
        }
        wtot[t] = w - orig;
    }
    __syncthreads();

    const unsigned base = wtot[t >> 6] + (inc - s);   // block-exclusive prefix for this thread
    u32x4* c4 = (u32x4*)cursor;
    #pragma unroll
    for (int k = 0; k < 8; ++k) {
        u32x4 o = { base + loc[4 * k + 0], base + loc[4 * k + 1],
                    base + loc[4 * k + 2], base + loc[4 * k + 3] };
        c4[t * 8 + k] = o;
    }
}

// 4 points per thread, 3x aligned 16B loads, scattered f32x4 stores
__global__ __launch_bounds__(256) void scatter_kernel(const float* __restrict__ xin,
                                                      unsigned* __restrict__ cursor,
                                                      f32x4* __restrict__ sortedx, int n) {
    const int j = blockIdx.x * blockDim.x + threadIdx.x;
    const int p0 = j * 4;
    if (p0 + 3 < n) {
        const f32x4* xb = (const f32x4*)(xin + (size_t)p0 * 3);
        const f32x4 a = __builtin_nontemporal_load(xb + 0);   // x0 y0 z0 x1
        const f32x4 b = __builtin_nontemporal_load(xb + 1);   // y1 z1 x2 y2
        const f32x4 c = __builtin_nontemporal_load(xb + 2);   // z2 x3 y3 z3
        const float X[4] = { a[0], a[3], b[2], c[1] };
        const float Y[4] = { a[1], b[0], b[3], c[2] };
        const float Z[4] = { a[2], b[1], c[0], c[3] };
        #pragma unroll
        for (int q = 0; q < 4; ++q) {
            const unsigned k = morton_key(X[q], Y[q], Z[q]);
            const unsigned slot = atomicAdd(&cursor[k], 1u);
            f32x4 v = { X[q], Y[q], Z[q], __uint_as_float((unsigned)(p0 + q)) };
            sortedx[slot] = v;
        }
    } else {
        for (int p = p0; p < n; ++p) {
            const size_t bb = 3ull * (size_t)p;
            const float px = xin[bb], py = xin[bb + 1], pz = xin[bb + 2];
            const unsigned k = morton_key(px, py, pz);
            const unsigned slot = atomicAdd(&cursor[k], 1u);
            f32x4 v = { px, py, pz, __uint_as_float((unsigned)p) };
            sortedx[slot] = v;
        }
    }
}

// Resolutions: floor(16 * 2^(l/3)) for l=0..15
__global__ __launch_bounds__(BLOCK, 8) void hashgrid_kernel(
    const float* __restrict__ xin, const f32x4* __restrict__ sortedx,
    const float* __restrict__ tables, float* __restrict__ out, int n, int sorted)
{
    __shared__ float lds[BLOCK * HP];
    __shared__ unsigned sorig[BLOCK];
    const int t = threadIdx.x;
    const int base = blockIdx.x * BLOCK;
    const int i = base + t;

    float px = 0.f, py = 0.f, pz = 0.f;
    unsigned orig = (unsigned)i;
    if (i < n) {
        if (sorted) {
            const f32x4 v = sortedx[i];
            px = v[0]; py = v[1]; pz = v[2];
            orig = __float_as_uint(v[3]);
        } else {
            const size_t xb = 3ull * (size_t)i;
            px = xin[xb + 0]; py = xin[xb + 1]; pz = xin[xb + 2];
        }
    }
    sorig[t] = orig;

    const float x01 = (px + 1.0f) * 0.5f;
    const float y01 = (py + 1.0f) * 0.5f;
    const float z01 = (pz + 1.0f) * 0.5f;

    constexpr int RES[16] = {16, 20, 25, 32, 40, 50, 64, 80,
                             101, 128, 161, 203, 256, 322, 406, 512};

    const int nf4 = min(n - base, BLOCK) * 4;   // valid float4s per half-store

    #pragma unroll
    for (int h = 0; h < 2; ++h) {
        #pragma unroll
        for (int lo = 0; lo < 8; ++lo) {
            const int l = h * 8 + lo;
            const float rf = (float)RES[l];
            const float xs = x01 * rf, ys = y01 * rf, zs = z01 * rf;
            const float fxs = floorf(xs), fys = floorf(ys), fzs = floorf(zs);
            const float tx = xs - fxs, ty = ys - fys, tz = zs - fzs;
            const unsigned xi = (unsigned)fxs;
            const unsigned yi = (unsigned)fys;
            const unsigned zi = (unsigned)fzs;

            // per-axis hash parts; (a^b)&m == (a&m)^(b&m); (v+1)*P == v*P + P (mod 2^32)
            const unsigned hx0 = xi & TMASK;      // PRIME[0]=1; upper-x hash = hx0 + 1
            const unsigned hym = yi * P2;
            const unsigned hy0 = hym & TMASK;
            const unsigned hy1 = (hym + P2) & TMASK;
            const unsigned hzm = zi * P3;
            const unsigned hz0 = hzm & TMASK;
            const unsigned hz1 = (hzm + P3) & TMASK;

            const float wx0 = 1.f - tx, wy0 = 1.f - ty, wz0 = 1.f - tz;
            const bool xeven = (xi & 1u) == 0u;
            const float* tbl = tables + (size_t)l * 65536ull;

            float a0 = 0.f, a1 = 0.f;
            #pragma unroll
            for (int p = 0; p < 4; ++p) {
                const unsigned m  = ((p & 1) ? hy1 : hy0) ^ ((p & 2) ? hz1 : hz0);
                const float  wyz  = ((p & 1) ? ty : wy0) * ((p & 2) ? tz : wz0);
                const unsigned idx0 = hx0 ^ m;
                const unsigned e    = idx0 & ~1u;
                // aligned 16B load covers entries {e, e+1}; if xi even, both x-corners
                const f32x4 q = *(const f32x4*)(tbl + 2u * e);
                const bool lo2 = (idx0 & 1u) == 0u;
                const float c0x = lo2 ? q[0] : q[2];
                const float c0y = lo2 ? q[1] : q[3];
                float c1x, c1y;
                if (xeven) {
                    c1x = lo2 ? q[2] : q[0];
                    c1y = lo2 ? q[3] : q[1];
                } else {
                    const unsigned idx1 = (hx0 + 1u) ^ m;
                    const float2 f = *(const float2*)(tbl + 2u * idx1);
                    c1x = f.x; c1y = f.y;
                }
                const float w0 = wyz * wx0;
                const float w1 = wyz * tx;
                a0 = fmaf(w0, c0x, fmaf(w1, c1x, a0));
                a1 = fmaf(w0, c0y, fmaf(w1, c1y, a1));
            }
            lds[t * HP + 2 * lo]     = a0;
            lds[t * HP + 2 * lo + 1] = a1;
        }

        __syncthreads();

        // store this half: 4 consecutive lanes emit one point's 64B half-row (full line)
        #pragma unroll
        for (int j = 0; j < 4; ++j) {
            const int g = j * BLOCK + t;
            if (g < nf4) {
                const int p = g >> 2;
                const int e = (g & 3) * 4;
                const float* s = &lds[p * HP + e];
                f32x4 v = { s[0], s[1], s[2], s[3] };
                __builtin_nontemporal_store(
                    v, (f32x4*)(out + (size_t)sorig[p] * 32ull + (size_t)(h * 16 + e)));
            }
        }
        __syncthreads();
    }
}

extern "C" void kernel_launch(void* const* d_in, const int* in_sizes, int n_in,
                              void* d_out, int out_size, void* d_ws, size_t ws_size,
                              hipStream_t stream) {
    const float* x      = (const float*)d_in[0];
    const float* tables = (const float*)d_in[1];
    float* out          = (float*)d_out;

    const int n = in_sizes[0] / 3;          // 1048576 points
    const int sorted = (ws_size >= WS_NEEDED) ? 1 : 0;

    f32x4* sortedx = (f32x4*)((char*)d_ws + WS_SORTED);

    if (sorted) {
        unsigned* hist   = (unsigned*)((char*)d_ws + WS_HIST);
        unsigned* cursor = (unsigned*)((char*)d_ws + WS_CURSOR);
        const int nq = (n + 3) / 4;         // threads for 4-pt kernels
        hipLaunchKernelGGL(zero_hist_kernel, dim3(NBINS / 256), dim3(256), 0, stream, hist);
        hipLaunchKernelGGL(hist_kernel, dim3((nq + 255) / 256), dim3(256), 0, stream,
                           x, hist, n);
        hipLaunchKernelGGL(scan_kernel, dim3(1), dim3(1024), 0, stream, hist, cursor);
        hipLaunchKernelGGL(scatter_kernel, dim3((nq + 255) / 256), dim3(256), 0, stream,
                           x, cursor, sortedx, n);
    }

    hipLaunchKernelGGL(hashgrid_kernel, dim3((n + BLOCK - 1) / BLOCK), dim3(BLOCK), 0, stream,
                       x, sortedx, tables, out, n, sorted);
}

// Round 7
// 353.077 us; speedup vs baseline: 1.7616x; 1.1127x over previous
//
#include <hip/hip_runtime.h>

#define TMASK 32767u
#define P2 2654435761u
#define P3 805459861u

typedef float f32x4 __attribute__((ext_vector_type(4)));
typedef unsigned u32x4 __attribute__((ext_vector_type(4)));

constexpr int NBINS = 32768;     // 32^3 Morton bins (~32 pts/bin at 1M points)
constexpr int BLOCK = 128;
constexpr int HP = 17;           // half-row pitch: 16 feats + 1 pad

// ---------- ws layout ----------
// [0,128K)   hist (32768 u32)
// [128K,256K) cursor (32768 u32, exclusive prefix)
// [256K,256K+4M) keyrank (n u32: rank<<15 | key)
// [+4M, +8M)  perm (n u32: sorted slot -> original point index)
constexpr size_t WS_HIST   = 0;
constexpr size_t WS_CURSOR = 128 * 1024;
constexpr size_t WS_KEYR   = 256 * 1024;
constexpr size_t WS_PERM   = WS_KEYR + (size_t)1048576 * 4;
constexpr size_t WS_NEEDED = WS_PERM + (size_t)1048576 * 4;

__device__ __forceinline__ unsigned part1by2(unsigned v) {
    v &= 0x3FFu;
    v = (v | (v << 16)) & 0x030000FFu;
    v = (v | (v << 8))  & 0x0300F00Fu;
    v = (v | (v << 4))  & 0x030C30C3u;
    v = (v | (v << 2))  & 0x09249249u;
    return v;
}

__device__ __forceinline__ unsigned morton_key(float px, float py, float pz) {
    const float x01 = (px + 1.0f) * 0.5f;
    const float y01 = (py + 1.0f) * 0.5f;
    const float z01 = (pz + 1.0f) * 0.5f;
    const unsigned cx = min(31u, (unsigned)(x01 * 32.0f));
    const unsigned cy = min(31u, (unsigned)(y01 * 32.0f));
    const unsigned cz = min(31u, (unsigned)(z01 * 32.0f));
    return part1by2(cx) | (part1by2(cy) << 1) | (part1by2(cz) << 2);
}

// 4 points/thread. atomicAdd's RETURN VALUE is the point's within-bin rank;
// save (rank<<15)|key so the later passes need no atomics at all.
__global__ __launch_bounds__(256) void hist_kernel(const float* __restrict__ xin,
                                                   unsigned* __restrict__ hist,
                                                   unsigned* __restrict__ keyrank, int n) {
    const int j = blockIdx.x * blockDim.x + threadIdx.x;
    const int p0 = j * 4;
    if (p0 + 3 < n) {
        const f32x4* xb = (const f32x4*)(xin + (size_t)p0 * 3);
        const f32x4 a = xb[0];   // x0 y0 z0 x1
        const f32x4 b = xb[1];   // y1 z1 x2 y2
        const f32x4 c = xb[2];   // z2 x3 y3 z3
        const unsigned k0 = morton_key(a[0], a[1], a[2]);
        const unsigned k1 = morton_key(a[3], b[0], b[1]);
        const unsigned k2 = morton_key(b[2], b[3], c[0]);
        const unsigned k3 = morton_key(c[1], c[2], c[3]);
        const unsigned r0 = atomicAdd(&hist[k0], 1u);
        const unsigned r1 = atomicAdd(&hist[k1], 1u);
        const unsigned r2 = atomicAdd(&hist[k2], 1u);
        const unsigned r3 = atomicAdd(&hist[k3], 1u);
        u32x4 kr = { (r0 << 15) | k0, (r1 << 15) | k1,
                     (r2 << 15) | k2, (r3 << 15) | k3 };
        *(u32x4*)(keyrank + p0) = kr;
    } else {
        for (int p = p0; p < n; ++p) {
            const size_t bb = 3ull * (size_t)p;
            const unsigned k = morton_key(xin[bb], xin[bb + 1], xin[bb + 2]);
            const unsigned r = atomicAdd(&hist[k], 1u);
            keyrank[p] = (r << 15) | k;
        }
    }
}

// exclusive scan of 32768 bins; 1024 threads, 32 bins each, shfl-based (2 barriers)
__global__ __launch_bounds__(1024) void scan_kernel(const unsigned* __restrict__ hist,
                                                    unsigned* __restrict__ cursor) {
    const int t = threadIdx.x;
    const u32x4* h4 = (const u32x4*)hist;
    u32x4 v[8];
    #pragma unroll
    for (int k = 0; k < 8; ++k) v[k] = h4[t * 8 + k];

    unsigned loc[32];
    unsigned s = 0;
    #pragma unroll
    for (int k = 0; k < 8; ++k) {
        loc[4 * k + 0] = s; s += v[k][0];
        loc[4 * k + 1] = s; s += v[k][1];
        loc[4 * k + 2] = s; s += v[k][2];
        loc[4 * k + 3] = s; s += v[k][3];
    }

    const int lane = t & 63;
    unsigned inc = s;
    #pragma unroll
    for (int off = 1; off < 64; off <<= 1) {
        const unsigned u = __shfl_up(inc, off, 64);
        if (lane >= off) inc += u;
    }

    __shared__ unsigned wtot[16];
    if (lane == 63) wtot[t >> 6] = inc;
    __syncthreads();
    if (t < 16) {
        unsigned w = wtot[t];
        const unsigned orig = w;
        #pragma unroll
        for (int off = 1; off < 16; off <<= 1) {
            const unsigned u = __shfl_up(w, off, 16);
            if (t >= off) w += u;
        }
        wtot[t] = w - orig;
    }
    __syncthreads();

    const unsigned base = wtot[t >> 6] + (inc - s);
    u32x4* c4 = (u32x4*)cursor;
    #pragma unroll
    for (int k = 0; k < 8; ++k) {
        u32x4 o = { base + loc[4 * k + 0], base + loc[4 * k + 1],
                    base + loc[4 * k + 2], base + loc[4 * k + 3] };
        c4[t * 8 + k] = o;
    }
}

// atomic-free scatter: slot = cursor[key] + rank; writes only the 4B permutation
__global__ __launch_bounds__(256) void scatter_kernel(const unsigned* __restrict__ keyrank,
                                                      const unsigned* __restrict__ cursor,
                                                      unsigned* __restrict__ perm, int n) {
    const int j = blockIdx.x * blockDim.x + threadIdx.x;
    const int p0 = j * 4;
    if (p0 + 3 < n) {
        const u32x4 kr = *(const u32x4*)(keyrank + p0);
        #pragma unroll
        for (int q = 0; q < 4; ++q) {
            const unsigned key  = kr[q] & TMASK;
            const unsigned rank = kr[q] >> 15;
            perm[cursor[key] + rank] = (unsigned)(p0 + q);
        }
    } else {
        for (int p = p0; p < n; ++p) {
            const unsigned krv  = keyrank[p];
            perm[cursor[krv & TMASK] + (krv >> 15)] = (unsigned)p;
        }
    }
}

// Resolutions: floor(16 * 2^(l/3)) for l=0..15
__global__ __launch_bounds__(BLOCK, 8) void hashgrid_kernel(
    const float* __restrict__ xin, const unsigned* __restrict__ perm,
    const float* __restrict__ tables, float* __restrict__ out, int n, int sorted)
{
    __shared__ float lds[BLOCK * HP];
    __shared__ unsigned sorig[BLOCK];
    const int t = threadIdx.x;
    const int base = blockIdx.x * BLOCK;
    const int i = base + t;

    float px = 0.f, py = 0.f, pz = 0.f;
    unsigned orig = (unsigned)i;
    if (i < n) {
        if (sorted) orig = perm[i];        // coalesced 4B read
        const size_t xb = 3ull * (size_t)orig;
        if ((int)orig + 1 < n) {           // 16B gather stays within the x allocation
            const f32x4 v = *(const f32x4*)(xin + xb);
            px = v[0]; py = v[1]; pz = v[2];
        } else {
            px = xin[xb]; py = xin[xb + 1]; pz = xin[xb + 2];
        }
    }
    sorig[t] = orig;

    const float x01 = (px + 1.0f) * 0.5f;
    const float y01 = (py + 1.0f) * 0.5f;
    const float z01 = (pz + 1.0f) * 0.5f;

    constexpr int RES[16] = {16, 20, 25, 32, 40, 50, 64, 80,
                             101, 128, 161, 203, 256, 322, 406, 512};

    const int nf4 = min(n - base, BLOCK) * 4;   // valid float4s per half-store

    #pragma unroll
    for (int h = 0; h < 2; ++h) {
        #pragma unroll
        for (int lo = 0; lo < 8; ++lo) {
            const int l = h * 8 + lo;
            const float rf = (float)RES[l];
            const float xs = x01 * rf, ys = y01 * rf, zs = z01 * rf;
            const float fxs = floorf(xs), fys = floorf(ys), fzs = floorf(zs);
            const float tx = xs - fxs, ty = ys - fys, tz = zs - fzs;
            const unsigned xi = (unsigned)fxs;
            const unsigned yi = (unsigned)fys;
            const unsigned zi = (unsigned)fzs;

            // per-axis hash parts; (a^b)&m == (a&m)^(b&m); (v+1)*P == v*P + P (mod 2^32)
            const unsigned hx0 = xi & TMASK;      // PRIME[0]=1; upper-x hash = hx0 + 1
            const unsigned hym = yi * P2;
            const unsigned hy0 = hym & TMASK;
            const unsigned hy1 = (hym + P2) & TMASK;
            const unsigned hzm = zi * P3;
            const unsigned hz0 = hzm & TMASK;
            const unsigned hz1 = (hzm + P3) & TMASK;

            const float wx0 = 1.f - tx, wy0 = 1.f - ty, wz0 = 1.f - tz;
            const bool xeven = (xi & 1u) == 0u;
            const float* tbl = tables + (size_t)l * 65536ull;

            float a0 = 0.f, a1 = 0.f;
            #pragma unroll
            for (int p = 0; p < 4; ++p) {
                const unsigned m  = ((p & 1) ? hy1 : hy0) ^ ((p & 2) ? hz1 : hz0);
                const float  wyz  = ((p & 1) ? ty : wy0) * ((p & 2) ? tz : wz0);
                const unsigned idx0 = hx0 ^ m;
                const unsigned e    = idx0 & ~1u;
                // aligned 16B load covers entries {e, e+1}; if xi even, both x-corners
                const f32x4 q = *(const f32x4*)(tbl + 2u * e);
                const bool lo2 = (idx0 & 1u) == 0u;
                const float c0x = lo2 ? q[0] : q[2];
                const float c0y = lo2 ? q[1] : q[3];
                float c1x, c1y;
                if (xeven) {
                    c1x = lo2 ? q[2] : q[0];
                    c1y = lo2 ? q[3] : q[1];
                } else {
                    const unsigned idx1 = (hx0 + 1u) ^ m;
                    const float2 f = *(const float2*)(tbl + 2u * idx1);
                    c1x = f.x; c1y = f.y;
                }
                const float w0 = wyz * wx0;
                const float w1 = wyz * tx;
                a0 = fmaf(w0, c0x, fmaf(w1, c1x, a0));
                a1 = fmaf(w0, c0y, fmaf(w1, c1y, a1));
            }
            lds[t * HP + 2 * lo]     = a0;
            lds[t * HP + 2 * lo + 1] = a1;
        }

        __syncthreads();

        // store this half: 4 consecutive lanes emit one point's 64B half-row (full line)
        #pragma unroll
        for (int j = 0; j < 4; ++j) {
            const int g = j * BLOCK + t;
            if (g < nf4) {
                const int p = g >> 2;
                const int e = (g & 3) * 4;
                const float* s = &lds[p * HP + e];
                f32x4 v = { s[0], s[1], s[2], s[3] };
                __builtin_nontemporal_store(
                    v, (f32x4*)(out + (size_t)sorig[p] * 32ull + (size_t)(h * 16 + e)));
            }
        }
        __syncthreads();
    }
}

extern "C" void kernel_launch(void* const* d_in, const int* in_sizes, int n_in,
                              void* d_out, int out_size, void* d_ws, size_t ws_size,
                              hipStream_t stream) {
    const float* x      = (const float*)d_in[0];
    const float* tables = (const float*)d_in[1];
    float* out          = (float*)d_out;

    const int n = in_sizes[0] / 3;          // 1048576 points
    const int sorted = (ws_size >= WS_NEEDED) ? 1 : 0;

    unsigned* perm = (unsigned*)((char*)d_ws + WS_PERM);

    if (sorted) {
        unsigned* hist    = (unsigned*)((char*)d_ws + WS_HIST);
        unsigned* cursor  = (unsigned*)((char*)d_ws + WS_CURSOR);
        unsigned* keyrank = (unsigned*)((char*)d_ws + WS_KEYR);
        const int nq = (n + 3) / 4;
        hipMemsetAsync(hist, 0, NBINS * sizeof(unsigned), stream);
        hipLaunchKernelGGL(hist_kernel, dim3((nq + 255) / 256), dim3(256), 0, stream,
                           x, hist, keyrank, n);
        hipLaunchKernelGGL(scan_kernel, dim3(1), dim3(1024), 0, stream, hist, cursor);
        hipLaunchKernelGGL(scatter_kernel, dim3((nq + 255) / 256), dim3(256), 0, stream,
                           keyrank, cursor, perm, n);
    }

    hipLaunchKernelGGL(hashgrid_kernel, dim3((n + BLOCK - 1) / BLOCK), dim3(BLOCK), 0, stream,
                       x, perm, tables, out, n, sorted);
}